// Round 8
// baseline (821.837 us; speedup 1.0000x reference)
//
#include <hip/hip_runtime.h>
#include <hip/hip_bf16.h>

// Problem constants (fixed by the reference)
#define B_ 1024
#define L_ 32
#define M_ 128
#define N_ 4096
#define S_ 32
#define ROWS (B_ * L_)          // 32768 rows of length N_

typedef __attribute__((ext_vector_type(8))) short    short8_t;   // 8 bf16 (4 VGPR)
typedef __attribute__((ext_vector_type(8))) unsigned short ushort8_t;
typedef __attribute__((ext_vector_type(4))) float    f32x4;

__device__ __forceinline__ unsigned short f2bf(float x) {  // RNE bf16
    unsigned u = __float_as_uint(x);
    unsigned r = (u + 0x7FFFu + ((u >> 16) & 1u)) >> 16;
    return (unsigned short)r;
}
__device__ __forceinline__ float bf2f(unsigned short h) {
    return __uint_as_float((unsigned)h << 16);
}

// ---------------------------------------------------------------------------
// K0: transpose W_d [L][M][N] -> W_dT [L][N][M] (runs AFTER encoder; WdT
// aliases the Wbf region)
// ---------------------------------------------------------------------------
__global__ __launch_bounds__(256) void transpose_wd(const float* __restrict__ Wd,
                                                    float* __restrict__ WdT) {
    __shared__ float t[32][33];
    int l = blockIdx.z;
    int n0 = blockIdx.x * 32, m0 = blockIdx.y * 32;
    int tx = threadIdx.x & 31, ty = threadIdx.x >> 5;
    const float* src = Wd + (size_t)l * M_ * N_;
    for (int i = ty; i < 32; i += 8)
        t[i][tx] = src[(size_t)(m0 + i) * N_ + n0 + tx];
    __syncthreads();
    float* dst = WdT + (size_t)l * N_ * M_;
    for (int i = ty; i < 32; i += 8)
        dst[(size_t)(n0 + i) * M_ + m0 + tx] = t[tx][i];
}

// ---------------------------------------------------------------------------
// K0b: c[l][n] = dot(b_d[l], W_e[l][n])
// ---------------------------------------------------------------------------
__global__ __launch_bounds__(256) void bias_dot(const float* __restrict__ We,
                                                const float* __restrict__ bd,
                                                float* __restrict__ c) {
    int l = blockIdx.y;
    int tid = threadIdx.x;
    int nl = tid >> 4, l16 = tid & 15;
    int n = blockIdx.x * 16 + nl;
    const float* w = We + ((size_t)l * N_ + n) * M_ + l16 * 8;
    const float* b = bd + l * M_ + l16 * 8;
    float4 w0 = *(const float4*)(w), w1 = *(const float4*)(w + 4);
    float4 b0 = *(const float4*)(b), b1 = *(const float4*)(b + 4);
    float s = w0.x*b0.x + w0.y*b0.y + w0.z*b0.z + w0.w*b0.w
            + w1.x*b1.x + w1.y*b1.y + w1.z*b1.z + w1.w*b1.w;
    #pragma unroll
    for (int o = 8; o > 0; o >>= 1) s += __shfl_xor(s, o, 64);
    if (l16 == 0) c[(size_t)l * N_ + n] = s;
}

// ---------------------------------------------------------------------------
// P1: split kin -> Abf [l][b][256] bf16: seg0 = a1 = bf16(k), seg1 = a2 = bf16(k-a1)
// ---------------------------------------------------------------------------
__global__ __launch_bounds__(256) void prep_a(const float* __restrict__ kin,
                                              unsigned short* __restrict__ Abf) {
    int g = blockIdx.x * 256 + threadIdx.x;       // over B*L*M
    int b = g >> 12, l = (g >> 7) & 31, m = g & 127;
    float x = kin[g];
    unsigned short a1 = f2bf(x);
    unsigned short a2 = f2bf(x - bf2f(a1));
    size_t base = ((size_t)l * B_ + b) * 256;
    Abf[base + m]       = a1;
    Abf[base + 128 + m] = a2;
}

// P2: split We -> Wbf [l][n][256] bf16: seg0 = w1, seg1 = w2
__global__ __launch_bounds__(256) void prep_w(const float* __restrict__ We,
                                              unsigned short* __restrict__ Wbf) {
    int g = blockIdx.x * 256 + threadIdx.x;       // over L*N*M
    int l = g >> 19, n = (g >> 7) & 4095, m = g & 127;
    float x = We[g];
    unsigned short w1 = f2bf(x);
    unsigned short w2 = f2bf(x - bf2f(w1));
    size_t base = ((size_t)l * N_ + n) * 256;
    Wbf[base + m]       = w1;
    Wbf[base + 128 + m] = w2;
}

// ---------------------------------------------------------------------------
// K1: encoder approx GEMM via MFMA bf16, 3-term split (unchanged from round 4)
// ---------------------------------------------------------------------------
__device__ __forceinline__ int swz(int row) { return (row & 3) ^ ((row >> 2) & 3); }

__global__ __launch_bounds__(256) void encoder_mfma(const unsigned short* __restrict__ Abf,
                                                    const unsigned short* __restrict__ Wbf,
                                                    const float* __restrict__ cvec,
                                                    unsigned short* __restrict__ y16) {
    const int l   = blockIdx.z;
    const int bn0 = blockIdx.x * 128;
    const int bm0 = blockIdx.y * 128;
    __shared__ __align__(16) unsigned short As[128 * 32];
    __shared__ __align__(16) unsigned short Bs[128 * 32];
    const int tid  = threadIdx.x;
    const int lane = tid & 63, wave = tid >> 6;
    const int wr = wave >> 1, wc = wave & 1;

    const unsigned short* Ab = Abf + ((size_t)l * B_ + bm0) * 256;
    const unsigned short* Wb = Wbf + ((size_t)l * N_ + bn0) * 256;

    auto stage = [&](int kA0, int kW0) {
        #pragma unroll
        for (int i = 0; i < 2; ++i) {
            int p   = i * 256 + tid;
            int row = p >> 2;
            int lc  = (p & 3) ^ swz(row);
            const unsigned short* g = Ab + (size_t)row * 256 + kA0 + lc * 8;
            unsigned dst = (unsigned)((i * 256 + (tid & ~63)) * 16);
            __builtin_amdgcn_global_load_lds(
                (const __attribute__((address_space(1))) void*)g,
                (__attribute__((address_space(3))) void*)((char*)As + dst), 16, 0, 0);
        }
        #pragma unroll
        for (int i = 0; i < 2; ++i) {
            int p   = i * 256 + tid;
            int row = p >> 2;
            int lc  = (p & 3) ^ swz(row);
            const unsigned short* g = Wb + (size_t)row * 256 + kW0 + lc * 8;
            unsigned dst = (unsigned)((i * 256 + (tid & ~63)) * 16);
            __builtin_amdgcn_global_load_lds(
                (const __attribute__((address_space(1))) void*)g,
                (__attribute__((address_space(3))) void*)((char*)Bs + dst), 16, 0, 0);
        }
    };

    f32x4 acc[4][4];
    #pragma unroll
    for (int i = 0; i < 4; ++i)
        #pragma unroll
        for (int j = 0; j < 4; ++j) acc[i][j] = (f32x4){0.f, 0.f, 0.f, 0.f};

    stage(0, 0);
    __syncthreads();

    #pragma unroll
    for (int t = 0; t < 12; ++t) {
        short8_t aF[4], bF[4];
        const int kg = lane >> 4;
        #pragma unroll
        for (int mt = 0; mt < 4; ++mt) {
            int row = wr * 64 + mt * 16 + (lane & 15);
            int pc  = kg ^ swz(row);
            aF[mt] = *reinterpret_cast<const short8_t*>(As + row * 32 + pc * 8);
        }
        #pragma unroll
        for (int nt = 0; nt < 4; ++nt) {
            int row = wc * 64 + nt * 16 + (lane & 15);
            int pc  = kg ^ swz(row);
            bF[nt] = *reinterpret_cast<const short8_t*>(Bs + row * 32 + pc * 8);
        }
        #pragma unroll
        for (int mt = 0; mt < 4; ++mt)
            #pragma unroll
            for (int nt = 0; nt < 4; ++nt)
                acc[mt][nt] = __builtin_amdgcn_mfma_f32_16x16x32_bf16(
                    aF[mt], bF[nt], acc[mt][nt], 0, 0, 0);

        if (t < 11) {
            int tn  = t + 1;
            int seg = tn >> 2, r = (tn & 3) * 32;
            int ka  = (seg == 2) ? 128 + r : r;
            int kw  = (seg == 1) ? 128 + r : r;
            __syncthreads();
            stage(ka, kw);
            __syncthreads();
        }
    }

    #pragma unroll
    for (int nt = 0; nt < 4; ++nt) {
        int n = bn0 + wc * 64 + nt * 16 + (lane & 15);
        float cj = cvec[(size_t)l * N_ + n];
        #pragma unroll
        for (int mt = 0; mt < 4; ++mt) {
            #pragma unroll
            for (int j = 0; j < 4; ++j) {
                int b = bm0 + wr * 64 + mt * 16 + (lane >> 4) * 4 + j;
                y16[((size_t)(b * L_ + l)) * 8192 + n] = f2bf(acc[mt][nt][j] - cj);
            }
        }
    }
}

// ---------------------------------------------------------------------------
// K2 (FUSED backend): per row -- select exact top-32, zero+scatter y, decode
// khat, residual partial. L-MAJOR block order so 1024 consecutive blocks share
// one layer's We slice (2MB) and WdT slice (2MB) -> L2-resident gathers.
// Select path = round-6/7's proven code (bisect, MARGIN 8e-4, r4-verbatim
// ascending-m recompute, exact rank). Zero-store issued early (r6's
// sched_barrier pattern) so write BW overlaps the latency-bound bisect.
// ---------------------------------------------------------------------------
#define POOL 64
#define MARGIN 8e-4f

__global__ __launch_bounds__(256) void topk_decode(float* __restrict__ y,
                                                   const float* __restrict__ We,
                                                   const float* __restrict__ WdT,
                                                   const float* __restrict__ kin,
                                                   const float* __restrict__ cvec,
                                                   float* __restrict__ khat,
                                                   float* __restrict__ partial) {
    const int bid = blockIdx.x;
    const int l = bid >> 10;                    // l-major: layer changes every 1024 blocks
    const int b = bid & 1023;
    const int row = b * L_ + l;
    const unsigned short* ya = (const unsigned short*)y + (size_t)row * 8192;
    float* yo = y + (size_t)row * N_;
    const int tid  = threadIdx.x;
    const int wave = tid >> 6, lane = tid & 63;

    __shared__ float kinL[M_];
    __shared__ float red_f[4];
    __shared__ int   red_i[2][4];
    __shared__ int   pidxS[POOL];
    __shared__ float pexS[POOL];
    __shared__ int   sidxL[S_];
    __shared__ float svalL[S_];
    __shared__ float red[128];
    __shared__ int   pcnt;

    if (tid < M_) kinL[tid] = kin[(size_t)row * M_ + tid];
    if (tid == 0) pcnt = 0;

    // load 16 approx values (two 16B loads), thread-local slots
    ushort8_t u0 = *reinterpret_cast<const ushort8_t*>(ya + tid * 8);
    ushort8_t u1 = *reinterpret_cast<const ushort8_t*>(ya + 2048 + tid * 8);
    float a[16];
    #pragma unroll
    for (int i = 0; i < 8; ++i) {
        a[i]     = fabsf(bf2f(u0[i]));
        a[8 + i] = fabsf(bf2f(u1[i]));
    }
    // Fence: conversions above force the loads' waitcnt; nothing below may be
    // hoisted above. Then overwrite the full row with zeros (write BW overlaps
    // the latency-bound bisect below; barriers drain vmcnt before the scatter).
    __builtin_amdgcn_sched_barrier(0);
    {
        float4 z = {0.f, 0.f, 0.f, 0.f};
        #pragma unroll
        for (int i = 0; i < 4; ++i)
            *reinterpret_cast<float4*>(yo + 4 * (tid + i * 256)) = z;
    }

    // block max (one barrier)
    float mx = 0.0f;
    #pragma unroll
    for (int i = 0; i < 16; ++i) mx = fmaxf(mx, a[i]);
    #pragma unroll
    for (int o = 32; o > 0; o >>= 1) mx = fmaxf(mx, __shfl_xor(mx, o, 64));
    if (lane == 0) red_f[wave] = mx;
    __syncthreads();
    mx = fmaxf(fmaxf(red_f[0], red_f[1]), fmaxf(red_f[2], red_f[3]));

    // bisect: invariant count(a >= lo) >= 32; tighten until count <= 40.
    // ONE barrier per iteration (alternating slots).
    float lo = 0.0f, hi = mx;
    int cl = N_;
    for (int it = 0; it < 30 && cl > 40; ++it) {
        float t = 0.5f * (lo + hi);
        int c = 0;
        #pragma unroll
        for (int i = 0; i < 16; ++i) c += (a[i] >= t) ? 1 : 0;
        #pragma unroll
        for (int o = 32; o > 0; o >>= 1) c += __shfl_xor(c, o, 64);
        if (lane == 0) red_i[it & 1][wave] = c;
        __syncthreads();
        c = red_i[it & 1][0] + red_i[it & 1][1] + red_i[it & 1][2] + red_i[it & 1][3];
        if (c >= S_) { lo = t; cl = c; } else { hi = t; }
    }

    // pool: everything with approx >= lo - MARGIN (provably covers exact top-32)
    const float th = lo - MARGIN;
    #pragma unroll
    for (int i = 0; i < 16; ++i) {
        if (a[i] >= th) {
            int p = atomicAdd(&pcnt, 1);
            if (p < POOL) pidxS[p] = (i < 8) ? (tid * 8 + i) : (2048 + tid * 8 + i - 8);
        }
    }
    __syncthreads();
    int c = pcnt < POOL ? pcnt : POOL;

    // exact recompute: ascending-m scalar fmaf chain from GLOBAL (We layer
    // slice is L2-resident thanks to l-major order). Verbatim r4/r7 code.
    for (int e = tid; e < c; e += 256) {
        int n = pidxS[e];
        const float* w = We + ((size_t)l * N_ + n) * M_;
        float acc = -cvec[(size_t)l * N_ + n];
        #pragma unroll 8
        for (int m = 0; m < M_; ++m) acc = fmaf(w[m], kinL[m], acc);
        pexS[e] = acc;
    }
    __syncthreads();

    // exact rank (lowest-index tie-break); winners scatter to y + LDS lists
    for (int e = tid; e < c; e += 256) {
        float ae = fabsf(pexS[e]);
        int   ne = pidxS[e];
        int rank = 0;
        for (int j = 0; j < c; ++j) {
            float aj = fabsf(pexS[j]);
            rank += ((aj > ae) || (aj == ae && pidxS[j] < ne)) ? 1 : 0;
        }
        if (rank < S_) {
            sidxL[rank] = ne;
            svalL[rank] = pexS[e];
            yo[ne] = pexS[e];     // zeros at this address drained by barriers above
        }
    }
    __syncthreads();

    // decode: thread m in [0,128) gathers 32 WdT rows (coalesced 512B, L2-hot)
    if (tid < M_) {
        const float* wt = WdT + (size_t)l * N_ * M_;
        float acc = 0.0f;
        #pragma unroll
        for (int j = 0; j < S_; ++j)
            acc = fmaf(svalL[j], wt[(size_t)sidxL[j] * M_ + tid], acc);
        khat[(size_t)row * M_ + tid] = acc;
        float r = acc - kinL[tid];
        red[tid] = r * r;
    }
    __syncthreads();
    for (int off = 64; off > 0; off >>= 1) {
        if (tid < off) red[tid] += red[tid + off];
        __syncthreads();
    }
    if (tid == 0) partial[row] = red[0];
}

// ---------------------------------------------------------------------------
// K4: deterministic reduction of 32768 partials -> loss
// ---------------------------------------------------------------------------
__global__ __launch_bounds__(256) void reduce_loss(const float* __restrict__ partial,
                                                   float* __restrict__ out_loss) {
    __shared__ float red[256];
    int tid = threadIdx.x;
    float s = 0.0f;
    for (int i = tid; i < ROWS; i += 256) s += partial[i];
    red[tid] = s;
    __syncthreads();
    for (int off = 128; off > 0; off >>= 1) {
        if (tid < off) red[tid] += red[tid + off];
        __syncthreads();
    }
    if (tid == 0) out_loss[0] = red[0] / (float)((size_t)B_ * L_ * M_);
}

// ---------------------------------------------------------------------------
extern "C" void kernel_launch(void* const* d_in, const int* in_sizes, int n_in,
                              void* d_out, int out_size, void* d_ws, size_t ws_size,
                              hipStream_t stream) {
    const float* kin = (const float*)d_in[0];   // [B][L][M]
    const float* We  = (const float*)d_in[1];   // [L][N][M]
    // d_in[2] = b_e (unused by reference encode())
    const float* Wd  = (const float*)d_in[3];   // [L][M][N]
    const float* bd  = (const float*)d_in[4];   // [L][M]
    // d_in[5] = s (==32, hardcoded)

    float* out   = (float*)d_out;
    float* loss  = out;                                   // [1]
    float* khat  = out + 1;                               // [B*L*M]
    float* y_out = out + 1 + (size_t)B_ * L_ * M_;        // [B*L*N]

    // workspace layout (region0 is shared: Wbf during encode, WdT after)
    char* ws = (char*)d_ws;
    unsigned short* Wbf = (unsigned short*)ws;                   // 64 MiB
    float*          WdT = (float*)ws;                            // 64 MiB (aliases Wbf)
    unsigned short* Abf = (unsigned short*)(ws + (64u << 20));   // 16 MiB
    float* cvec    = (float*)(ws + (80u << 20));                 // 512 KiB
    float* partial = (float*)(ws + (81u << 20));                 // 128 KiB

    bias_dot<<<dim3(N_ / 16, L_), 256, 0, stream>>>(We, bd, cvec);
    prep_a<<<(B_ * L_ * M_) / 256, 256, 0, stream>>>(kin, Abf);
    prep_w<<<(L_ * N_ * M_) / 256, 256, 0, stream>>>(We, Wbf);
    encoder_mfma<<<dim3(N_ / 128, B_ / 128, L_), 256, 0, stream>>>(
        Abf, Wbf, cvec, (unsigned short*)y_out);
    // Wbf dead now; transpose overwrites region0 with WdT
    transpose_wd<<<dim3(N_ / 32, M_ / 32, L_), 256, 0, stream>>>(Wd, WdT);
    // fused backend: select + zero/scatter y + decode + residual partials
    topk_decode<<<ROWS, 256, 0, stream>>>(y_out, We, WdT, kin, cvec, khat, partial);
    reduce_loss<<<1, 256, 0, stream>>>(partial, loss);
}

// Round 9
// 750.721 us; speedup vs baseline: 1.0947x; 1.0947x over previous
//
#include <hip/hip_runtime.h>
#include <hip/hip_bf16.h>

// Problem constants (fixed by the reference)
#define B_ 1024
#define L_ 32
#define M_ 128
#define N_ 4096
#define S_ 32
#define ROWS (B_ * L_)          // 32768 rows of length N_

typedef __attribute__((ext_vector_type(8))) short    short8_t;   // 8 bf16 (4 VGPR)
typedef __attribute__((ext_vector_type(8))) unsigned short ushort8_t;
typedef __attribute__((ext_vector_type(4))) float    f32x4;

__device__ __forceinline__ unsigned short f2bf(float x) {  // RNE bf16
    unsigned u = __float_as_uint(x);
    unsigned r = (u + 0x7FFFu + ((u >> 16) & 1u)) >> 16;
    return (unsigned short)r;
}
__device__ __forceinline__ float bf2f(unsigned short h) {
    return __uint_as_float((unsigned)h << 16);
}

// ---------------------------------------------------------------------------
// K0: transpose W_d [L][M][N] -> W_dT [L][N][M] (runs AFTER encoder; WdT
// aliases the Wbf region)
// ---------------------------------------------------------------------------
__global__ __launch_bounds__(256) void transpose_wd(const float* __restrict__ Wd,
                                                    float* __restrict__ WdT) {
    __shared__ float t[32][33];
    int l = blockIdx.z;
    int n0 = blockIdx.x * 32, m0 = blockIdx.y * 32;
    int tx = threadIdx.x & 31, ty = threadIdx.x >> 5;
    const float* src = Wd + (size_t)l * M_ * N_;
    for (int i = ty; i < 32; i += 8)
        t[i][tx] = src[(size_t)(m0 + i) * N_ + n0 + tx];
    __syncthreads();
    float* dst = WdT + (size_t)l * N_ * M_;
    for (int i = ty; i < 32; i += 8)
        dst[(size_t)(n0 + i) * M_ + m0 + tx] = t[tx][i];
}

// ---------------------------------------------------------------------------
// P1: prep W (FUSED with bias_dot): one pass over We producing
//   Wbf[l][n][128] = bf16(We row)   and   cvec[l][n] = dot(b_d[l], We[l][n])
// 16 threads per n-row (2 float4 reads each), 16 rows per block.
// ---------------------------------------------------------------------------
__global__ __launch_bounds__(256) void prep_w(const float* __restrict__ We,
                                              const float* __restrict__ bd,
                                              unsigned short* __restrict__ Wbf,
                                              float* __restrict__ cvec) {
    int l = blockIdx.y;
    int tid = threadIdx.x;
    int nl = tid >> 4, t = tid & 15;
    int n = blockIdx.x * 16 + nl;
    const float* w = We + ((size_t)l * N_ + n) * M_ + t * 8;
    const float* b = bd + l * M_ + t * 8;
    float4 w0 = *(const float4*)(w), w1 = *(const float4*)(w + 4);
    float4 b0 = *(const float4*)(b), b1 = *(const float4*)(b + 4);
    // bf16 pack (8 values, 16B store, coalesced within the 16-thread group)
    ushort8_t o;
    o[0] = f2bf(w0.x); o[1] = f2bf(w0.y); o[2] = f2bf(w0.z); o[3] = f2bf(w0.w);
    o[4] = f2bf(w1.x); o[5] = f2bf(w1.y); o[6] = f2bf(w1.z); o[7] = f2bf(w1.w);
    *reinterpret_cast<ushort8_t*>(Wbf + ((size_t)l * N_ + n) * 128 + t * 8) = o;
    // bias dot (b_d is zero in this setup, but keep the general path)
    float s = w0.x*b0.x + w0.y*b0.y + w0.z*b0.z + w0.w*b0.w
            + w1.x*b1.x + w1.y*b1.y + w1.z*b1.z + w1.w*b1.w;
    #pragma unroll
    for (int oo = 8; oo > 0; oo >>= 1) s += __shfl_xor(s, oo, 64);
    if (t == 0) cvec[(size_t)l * N_ + n] = s;
}

// P2: prep A: Abf[l][b][128] = bf16(kin[b][l][:])
__global__ __launch_bounds__(256) void prep_a(const float* __restrict__ kin,
                                              unsigned short* __restrict__ Abf) {
    int g = blockIdx.x * 256 + threadIdx.x;       // over B*L*M
    int b = g >> 12, l = (g >> 7) & 31, m = g & 127;
    Abf[(((size_t)l * B_ + b) << 7) + m] = f2bf(kin[g]);
}

// ---------------------------------------------------------------------------
// K1: encoder approx GEMM via MFMA bf16, SINGLE term (K=128, 4 BK=32 steps).
// Selection-only approximation; winners are recomputed exactly later.
// 128x128 tile, 4 waves, 16x16x32 MFMA, global_load_lds staging with
// inverse-chunk-swizzled source, chunk-XOR LDS swizzle.
// ---------------------------------------------------------------------------
__device__ __forceinline__ int swz(int row) { return (row & 3) ^ ((row >> 2) & 3); }

__global__ __launch_bounds__(256) void encoder_mfma(const unsigned short* __restrict__ Abf,
                                                    const unsigned short* __restrict__ Wbf,
                                                    const float* __restrict__ cvec,
                                                    unsigned short* __restrict__ y16) {
    const int l   = blockIdx.z;
    const int bn0 = blockIdx.x * 128;
    const int bm0 = blockIdx.y * 128;
    __shared__ __align__(16) unsigned short As[128 * 32];
    __shared__ __align__(16) unsigned short Bs[128 * 32];
    const int tid  = threadIdx.x;
    const int lane = tid & 63, wave = tid >> 6;
    const int wr = wave >> 1, wc = wave & 1;

    const unsigned short* Ab = Abf + (((size_t)l * B_ + bm0) << 7);
    const unsigned short* Wb = Wbf + (((size_t)l * N_ + bn0) << 7);

    auto stage = [&](int k0) {
        #pragma unroll
        for (int i = 0; i < 2; ++i) {
            int p   = i * 256 + tid;              // float4-slot 0..511
            int row = p >> 2;
            int lc  = (p & 3) ^ swz(row);         // inverse swizzle on SOURCE
            const unsigned short* g = Ab + ((size_t)row << 7) + k0 + lc * 8;
            unsigned dst = (unsigned)((i * 256 + (tid & ~63)) * 16);
            __builtin_amdgcn_global_load_lds(
                (const __attribute__((address_space(1))) void*)g,
                (__attribute__((address_space(3))) void*)((char*)As + dst), 16, 0, 0);
        }
        #pragma unroll
        for (int i = 0; i < 2; ++i) {
            int p   = i * 256 + tid;
            int row = p >> 2;
            int lc  = (p & 3) ^ swz(row);
            const unsigned short* g = Wb + ((size_t)row << 7) + k0 + lc * 8;
            unsigned dst = (unsigned)((i * 256 + (tid & ~63)) * 16);
            __builtin_amdgcn_global_load_lds(
                (const __attribute__((address_space(1))) void*)g,
                (__attribute__((address_space(3))) void*)((char*)Bs + dst), 16, 0, 0);
        }
    };

    f32x4 acc[4][4];
    #pragma unroll
    for (int i = 0; i < 4; ++i)
        #pragma unroll
        for (int j = 0; j < 4; ++j) acc[i][j] = (f32x4){0.f, 0.f, 0.f, 0.f};

    stage(0);
    __syncthreads();

    #pragma unroll
    for (int t = 0; t < 4; ++t) {
        short8_t aF[4], bF[4];
        const int kg = lane >> 4;
        #pragma unroll
        for (int mt = 0; mt < 4; ++mt) {
            int row = wr * 64 + mt * 16 + (lane & 15);
            int pc  = kg ^ swz(row);
            aF[mt] = *reinterpret_cast<const short8_t*>(As + row * 32 + pc * 8);
        }
        #pragma unroll
        for (int nt = 0; nt < 4; ++nt) {
            int row = wc * 64 + nt * 16 + (lane & 15);
            int pc  = kg ^ swz(row);
            bF[nt] = *reinterpret_cast<const short8_t*>(Bs + row * 32 + pc * 8);
        }
        #pragma unroll
        for (int mt = 0; mt < 4; ++mt)
            #pragma unroll
            for (int nt = 0; nt < 4; ++nt)
                acc[mt][nt] = __builtin_amdgcn_mfma_f32_16x16x32_bf16(
                    aF[mt], bF[nt], acc[mt][nt], 0, 0, 0);

        if (t < 3) {
            __syncthreads();
            stage((t + 1) * 32);
            __syncthreads();
        }
    }

    // epilogue: bf16 approx into the low 8KB of each row's 16KB slot
    #pragma unroll
    for (int nt = 0; nt < 4; ++nt) {
        int n = bn0 + wc * 64 + nt * 16 + (lane & 15);
        float cj = cvec[(size_t)l * N_ + n];
        #pragma unroll
        for (int mt = 0; mt < 4; ++mt) {
            #pragma unroll
            for (int j = 0; j < 4; ++j) {
                int b = bm0 + wr * 64 + mt * 16 + (lane >> 4) * 4 + j;
                y16[((size_t)(b * L_ + l)) * 8192 + n] = f2bf(acc[mt][nt][j] - cj);
            }
        }
    }
}

// ---------------------------------------------------------------------------
// K2 (FUSED backend): select exact top-32, zero+scatter y, decode khat,
// residual partial. REVERSED l-major block order: l = 31 - bid>>10 so the
// most-recently-written approx rows (encoder z = l dispatches last) are read
// first -> L3 recency hits; 1024 consecutive blocks share one layer's
// We/WdT slices -> L2-resident gathers.
// MARGIN 1.2e-3 covers single-term bf16 approx error (2*eps ~ 9e-4).
// ---------------------------------------------------------------------------
#define POOL 96
#define MARGIN 1.2e-3f

__global__ __launch_bounds__(256) void topk_decode(float* __restrict__ y,
                                                   const float* __restrict__ We,
                                                   const float* __restrict__ WdT,
                                                   const float* __restrict__ kin,
                                                   const float* __restrict__ cvec,
                                                   float* __restrict__ khat,
                                                   float* __restrict__ partial) {
    const int bid = blockIdx.x;
    const int l = 31 - (bid >> 10);             // reversed l-major
    const int b = bid & 1023;
    const int row = b * L_ + l;
    const unsigned short* ya = (const unsigned short*)y + (size_t)row * 8192;
    float* yo = y + (size_t)row * N_;
    const int tid  = threadIdx.x;
    const int wave = tid >> 6, lane = tid & 63;

    __shared__ float kinL[M_];
    __shared__ float red_f[4];
    __shared__ int   red_i[2][4];
    __shared__ int   pidxS[POOL];
    __shared__ float pexS[POOL];
    __shared__ int   sidxL[S_];
    __shared__ float svalL[S_];
    __shared__ float red[128];
    __shared__ int   pcnt;

    if (tid < M_) kinL[tid] = kin[(size_t)row * M_ + tid];
    if (tid == 0) pcnt = 0;

    // load 16 approx values (two 16B loads), thread-local slots
    ushort8_t u0 = *reinterpret_cast<const ushort8_t*>(ya + tid * 8);
    ushort8_t u1 = *reinterpret_cast<const ushort8_t*>(ya + 2048 + tid * 8);
    float a[16];
    #pragma unroll
    for (int i = 0; i < 8; ++i) {
        a[i]     = fabsf(bf2f(u0[i]));
        a[8 + i] = fabsf(bf2f(u1[i]));
    }
    // Fence, then early zero-store of the full row (overlaps the bisect).
    __builtin_amdgcn_sched_barrier(0);
    {
        float4 z = {0.f, 0.f, 0.f, 0.f};
        #pragma unroll
        for (int i = 0; i < 4; ++i)
            *reinterpret_cast<float4*>(yo + 4 * (tid + i * 256)) = z;
    }

    // block max (one barrier)
    float mx = 0.0f;
    #pragma unroll
    for (int i = 0; i < 16; ++i) mx = fmaxf(mx, a[i]);
    #pragma unroll
    for (int o = 32; o > 0; o >>= 1) mx = fmaxf(mx, __shfl_xor(mx, o, 64));
    if (lane == 0) red_f[wave] = mx;
    __syncthreads();
    mx = fmaxf(fmaxf(red_f[0], red_f[1]), fmaxf(red_f[2], red_f[3]));

    // bisect: invariant count(a >= lo) >= 32; tighten until count <= 40.
    float lo = 0.0f, hi = mx;
    int cl = N_;
    for (int it = 0; it < 30 && cl > 40; ++it) {
        float t = 0.5f * (lo + hi);
        int c = 0;
        #pragma unroll
        for (int i = 0; i < 16; ++i) c += (a[i] >= t) ? 1 : 0;
        #pragma unroll
        for (int o = 32; o > 0; o >>= 1) c += __shfl_xor(c, o, 64);
        if (lane == 0) red_i[it & 1][wave] = c;
        __syncthreads();
        c = red_i[it & 1][0] + red_i[it & 1][1] + red_i[it & 1][2] + red_i[it & 1][3];
        if (c >= S_) { lo = t; cl = c; } else { hi = t; }
    }

    // pool: everything with approx >= lo - MARGIN (covers exact top-32)
    const float th = lo - MARGIN;
    #pragma unroll
    for (int i = 0; i < 16; ++i) {
        if (a[i] >= th) {
            int p = atomicAdd(&pcnt, 1);
            if (p < POOL) pidxS[p] = (i < 8) ? (tid * 8 + i) : (2048 + tid * 8 + i - 8);
        }
    }
    __syncthreads();
    int c = pcnt < POOL ? pcnt : POOL;

    // exact recompute: ascending-m scalar fmaf chain from GLOBAL (We layer
    // slice L2-resident). Verbatim r4/r7/r8 passing code.
    for (int e = tid; e < c; e += 256) {
        int n = pidxS[e];
        const float* w = We + ((size_t)l * N_ + n) * M_;
        float acc = -cvec[(size_t)l * N_ + n];
        #pragma unroll 8
        for (int m = 0; m < M_; ++m) acc = fmaf(w[m], kinL[m], acc);
        pexS[e] = acc;
    }
    __syncthreads();

    // exact rank (lowest-index tie-break); winners scatter to y + LDS lists
    for (int e = tid; e < c; e += 256) {
        float ae = fabsf(pexS[e]);
        int   ne = pidxS[e];
        int rank = 0;
        for (int j = 0; j < c; ++j) {
            float aj = fabsf(pexS[j]);
            rank += ((aj > ae) || (aj == ae && pidxS[j] < ne)) ? 1 : 0;
        }
        if (rank < S_) {
            sidxL[rank] = ne;
            svalL[rank] = pexS[e];
            yo[ne] = pexS[e];
        }
    }
    __syncthreads();

    // decode: thread m in [0,128) gathers 32 WdT rows (coalesced 512B, L2-hot)
    if (tid < M_) {
        const float* wt = WdT + (size_t)l * N_ * M_;
        float acc = 0.0f;
        #pragma unroll
        for (int j = 0; j < S_; ++j)
            acc = fmaf(svalL[j], wt[(size_t)sidxL[j] * M_ + tid], acc);
        khat[(size_t)row * M_ + tid] = acc;
        float r = acc - kinL[tid];
        red[tid] = r * r;
    }
    __syncthreads();
    for (int off = 64; off > 0; off >>= 1) {
        if (tid < off) red[tid] += red[tid + off];
        __syncthreads();
    }
    if (tid == 0) partial[row] = red[0];
}

// ---------------------------------------------------------------------------
// K4: deterministic reduction of 32768 partials -> loss
// ---------------------------------------------------------------------------
__global__ __launch_bounds__(256) void reduce_loss(const float* __restrict__ partial,
                                                   float* __restrict__ out_loss) {
    __shared__ float red[256];
    int tid = threadIdx.x;
    float s = 0.0f;
    for (int i = tid; i < ROWS; i += 256) s += partial[i];
    red[tid] = s;
    __syncthreads();
    for (int off = 128; off > 0; off >>= 1) {
        if (tid < off) red[tid] += red[tid + off];
        __syncthreads();
    }
    if (tid == 0) out_loss[0] = red[0] / (float)((size_t)B_ * L_ * M_);
}

// ---------------------------------------------------------------------------
extern "C" void kernel_launch(void* const* d_in, const int* in_sizes, int n_in,
                              void* d_out, int out_size, void* d_ws, size_t ws_size,
                              hipStream_t stream) {
    const float* kin = (const float*)d_in[0];   // [B][L][M]
    const float* We  = (const float*)d_in[1];   // [L][N][M]
    // d_in[2] = b_e (unused by reference encode())
    const float* Wd  = (const float*)d_in[3];   // [L][M][N]
    const float* bd  = (const float*)d_in[4];   // [L][M]
    // d_in[5] = s (==32, hardcoded)

    float* out   = (float*)d_out;
    float* loss  = out;                                   // [1]
    float* khat  = out + 1;                               // [B*L*M]
    float* y_out = out + 1 + (size_t)B_ * L_ * M_;        // [B*L*N]

    // workspace layout (region0 shared: Wbf during encode, WdT after)
    char* ws = (char*)d_ws;
    unsigned short* Wbf = (unsigned short*)ws;                   // 32 MiB (in 64 MiB region0)
    float*          WdT = (float*)ws;                            // 64 MiB (aliases Wbf)
    unsigned short* Abf = (unsigned short*)(ws + (64u << 20));   // 8 MiB
    float* cvec    = (float*)(ws + (80u << 20));                 // 512 KiB
    float* partial = (float*)(ws + (81u << 20));                 // 128 KiB

    prep_w<<<dim3(N_ / 16, L_), 256, 0, stream>>>(We, bd, Wbf, cvec);
    prep_a<<<(B_ * L_ * M_) / 256, 256, 0, stream>>>(kin, Abf);
    encoder_mfma<<<dim3(N_ / 128, B_ / 128, L_), 256, 0, stream>>>(
        Abf, Wbf, cvec, (unsigned short*)y_out);
    // Wbf dead now; transpose overwrites region0 with WdT
    transpose_wd<<<dim3(N_ / 32, M_ / 32, L_), 256, 0, stream>>>(Wd, WdT);
    // fused backend: select + zero/scatter y + decode + residual partials
    topk_decode<<<ROWS, 256, 0, stream>>>(y_out, We, WdT, kin, cvec, khat, partial);
    reduce_loss<<<1, 256, 0, stream>>>(partial, loss);
}

// Round 10
// 732.093 us; speedup vs baseline: 1.1226x; 1.0254x over previous
//
#include <hip/hip_runtime.h>
#include <hip/hip_bf16.h>

// Problem constants (fixed by the reference)
#define B_ 1024
#define L_ 32
#define M_ 128
#define N_ 4096
#define S_ 32
#define ROWS (B_ * L_)          // 32768 rows of length N_

typedef __attribute__((ext_vector_type(8))) short    short8_t;   // 8 bf16 (4 VGPR)
typedef __attribute__((ext_vector_type(8))) unsigned short ushort8_t;
typedef __attribute__((ext_vector_type(4))) float    f32x4;

__device__ __forceinline__ unsigned short f2bf(float x) {  // RNE bf16
    unsigned u = __float_as_uint(x);
    unsigned r = (u + 0x7FFFu + ((u >> 16) & 1u)) >> 16;
    return (unsigned short)r;
}
__device__ __forceinline__ float bf2f(unsigned short h) {
    return __uint_as_float((unsigned)h << 16);
}

// ---------------------------------------------------------------------------
// K0: transpose W_d [L][M][N] -> W_dT [L][N][M] (runs AFTER encoder; WdT
// aliases the Wbf region)
// ---------------------------------------------------------------------------
__global__ __launch_bounds__(256) void transpose_wd(const float* __restrict__ Wd,
                                                    float* __restrict__ WdT) {
    __shared__ float t[32][33];
    int l = blockIdx.z;
    int n0 = blockIdx.x * 32, m0 = blockIdx.y * 32;
    int tx = threadIdx.x & 31, ty = threadIdx.x >> 5;
    const float* src = Wd + (size_t)l * M_ * N_;
    for (int i = ty; i < 32; i += 8)
        t[i][tx] = src[(size_t)(m0 + i) * N_ + n0 + tx];
    __syncthreads();
    float* dst = WdT + (size_t)l * N_ * M_;
    for (int i = ty; i < 32; i += 8)
        dst[(size_t)(n0 + i) * M_ + m0 + tx] = t[tx][i];
}

// ---------------------------------------------------------------------------
// Z: zero the LOW 8KB half of every y row slot (pure streaming, full BW).
// The encoder writes approx into the HIGH half, so this is safe to run early.
// ---------------------------------------------------------------------------
__global__ __launch_bounds__(256) void zero_y_low(float* __restrict__ y) {
    const float4 z = {0.f, 0.f, 0.f, 0.f};
    int idx = blockIdx.x * 256 + threadIdx.x;
    // total low-half float4s: ROWS * 512 = 16,777,216; grid 2048*256 threads
    for (int i = idx; i < ROWS * 512; i += 2048 * 256) {
        int row = i >> 9, slot = i & 511;
        reinterpret_cast<float4*>(y + (size_t)row * N_)[slot] = z;
    }
}

// ---------------------------------------------------------------------------
// P1: prep W (fused bias_dot): Wbf[l][n][128] = bf16(We row); cvec = b_d . We_n
// ---------------------------------------------------------------------------
__global__ __launch_bounds__(256) void prep_w(const float* __restrict__ We,
                                              const float* __restrict__ bd,
                                              unsigned short* __restrict__ Wbf,
                                              float* __restrict__ cvec) {
    int l = blockIdx.y;
    int tid = threadIdx.x;
    int nl = tid >> 4, t = tid & 15;
    int n = blockIdx.x * 16 + nl;
    const float* w = We + ((size_t)l * N_ + n) * M_ + t * 8;
    const float* b = bd + l * M_ + t * 8;
    float4 w0 = *(const float4*)(w), w1 = *(const float4*)(w + 4);
    float4 b0 = *(const float4*)(b), b1 = *(const float4*)(b + 4);
    ushort8_t o;
    o[0] = f2bf(w0.x); o[1] = f2bf(w0.y); o[2] = f2bf(w0.z); o[3] = f2bf(w0.w);
    o[4] = f2bf(w1.x); o[5] = f2bf(w1.y); o[6] = f2bf(w1.z); o[7] = f2bf(w1.w);
    *reinterpret_cast<ushort8_t*>(Wbf + ((size_t)l * N_ + n) * 128 + t * 8) = o;
    float s = w0.x*b0.x + w0.y*b0.y + w0.z*b0.z + w0.w*b0.w
            + w1.x*b1.x + w1.y*b1.y + w1.z*b1.z + w1.w*b1.w;
    #pragma unroll
    for (int oo = 8; oo > 0; oo >>= 1) s += __shfl_xor(s, oo, 64);
    if (t == 0) cvec[(size_t)l * N_ + n] = s;
}

// P2: prep A: Abf[l][b][128] = bf16(kin[b][l][:])
__global__ __launch_bounds__(256) void prep_a(const float* __restrict__ kin,
                                              unsigned short* __restrict__ Abf) {
    int g = blockIdx.x * 256 + threadIdx.x;       // over B*L*M
    int b = g >> 12, l = (g >> 7) & 31, m = g & 127;
    Abf[(((size_t)l * B_ + b) << 7) + m] = f2bf(kin[g]);
}

// ---------------------------------------------------------------------------
// K1: encoder approx GEMM via MFMA bf16, single term (K=128, 4 BK=32 steps).
// Approx bf16 goes into the HIGH 8KB half of each row's 16KB y slot.
// ---------------------------------------------------------------------------
__device__ __forceinline__ int swz(int row) { return (row & 3) ^ ((row >> 2) & 3); }

__global__ __launch_bounds__(256) void encoder_mfma(const unsigned short* __restrict__ Abf,
                                                    const unsigned short* __restrict__ Wbf,
                                                    const float* __restrict__ cvec,
                                                    unsigned short* __restrict__ y16) {
    const int l   = blockIdx.z;
    const int bn0 = blockIdx.x * 128;
    const int bm0 = blockIdx.y * 128;
    __shared__ __align__(16) unsigned short As[128 * 32];
    __shared__ __align__(16) unsigned short Bs[128 * 32];
    const int tid  = threadIdx.x;
    const int lane = tid & 63, wave = tid >> 6;
    const int wr = wave >> 1, wc = wave & 1;

    const unsigned short* Ab = Abf + (((size_t)l * B_ + bm0) << 7);
    const unsigned short* Wb = Wbf + (((size_t)l * N_ + bn0) << 7);

    auto stage = [&](int k0) {
        #pragma unroll
        for (int i = 0; i < 2; ++i) {
            int p   = i * 256 + tid;
            int row = p >> 2;
            int lc  = (p & 3) ^ swz(row);
            const unsigned short* g = Ab + ((size_t)row << 7) + k0 + lc * 8;
            unsigned dst = (unsigned)((i * 256 + (tid & ~63)) * 16);
            __builtin_amdgcn_global_load_lds(
                (const __attribute__((address_space(1))) void*)g,
                (__attribute__((address_space(3))) void*)((char*)As + dst), 16, 0, 0);
        }
        #pragma unroll
        for (int i = 0; i < 2; ++i) {
            int p   = i * 256 + tid;
            int row = p >> 2;
            int lc  = (p & 3) ^ swz(row);
            const unsigned short* g = Wb + ((size_t)row << 7) + k0 + lc * 8;
            unsigned dst = (unsigned)((i * 256 + (tid & ~63)) * 16);
            __builtin_amdgcn_global_load_lds(
                (const __attribute__((address_space(1))) void*)g,
                (__attribute__((address_space(3))) void*)((char*)Bs + dst), 16, 0, 0);
        }
    };

    f32x4 acc[4][4];
    #pragma unroll
    for (int i = 0; i < 4; ++i)
        #pragma unroll
        for (int j = 0; j < 4; ++j) acc[i][j] = (f32x4){0.f, 0.f, 0.f, 0.f};

    stage(0);
    __syncthreads();

    #pragma unroll
    for (int t = 0; t < 4; ++t) {
        short8_t aF[4], bF[4];
        const int kg = lane >> 4;
        #pragma unroll
        for (int mt = 0; mt < 4; ++mt) {
            int row = wr * 64 + mt * 16 + (lane & 15);
            int pc  = kg ^ swz(row);
            aF[mt] = *reinterpret_cast<const short8_t*>(As + row * 32 + pc * 8);
        }
        #pragma unroll
        for (int nt = 0; nt < 4; ++nt) {
            int row = wc * 64 + nt * 16 + (lane & 15);
            int pc  = kg ^ swz(row);
            bF[nt] = *reinterpret_cast<const short8_t*>(Bs + row * 32 + pc * 8);
        }
        #pragma unroll
        for (int mt = 0; mt < 4; ++mt)
            #pragma unroll
            for (int nt = 0; nt < 4; ++nt)
                acc[mt][nt] = __builtin_amdgcn_mfma_f32_16x16x32_bf16(
                    aF[mt], bF[nt], acc[mt][nt], 0, 0, 0);

        if (t < 3) {
            __syncthreads();
            stage((t + 1) * 32);
            __syncthreads();
        }
    }

    // epilogue: bf16 approx into the HIGH 8KB half of each row slot
    #pragma unroll
    for (int nt = 0; nt < 4; ++nt) {
        int n = bn0 + wc * 64 + nt * 16 + (lane & 15);
        float cj = cvec[(size_t)l * N_ + n];
        #pragma unroll
        for (int mt = 0; mt < 4; ++mt) {
            #pragma unroll
            for (int j = 0; j < 4; ++j) {
                int b = bm0 + wr * 64 + mt * 16 + (lane >> 4) * 4 + j;
                y16[((size_t)(b * L_ + l)) * 8192 + 4096 + n] = f2bf(acc[mt][nt][j] - cj);
            }
        }
    }
}

// ---------------------------------------------------------------------------
// K2 (wave-per-row fused backend, ZERO block barriers):
// one 64-lane wave owns one row. 64 approx values in VGPRs; wave max + bisect
// via shfl only; pool via wave-local LDS atomics; r4-verbatim ascending-m
// exact recompute (1-2 candidates/lane); exact rank; vmcnt(0) drain; scatter
// winners; fused decode (2 dims/lane) + residual shfl-reduce.
// L-major wave order: 1024 consecutive waves share one layer's We/WdT slices.
// ---------------------------------------------------------------------------
#define POOL 96
#define MARGIN 1.2e-3f

__global__ __launch_bounds__(256) void topk_decode(float* __restrict__ y,
                                                   const float* __restrict__ We,
                                                   const float* __restrict__ WdT,
                                                   const float* __restrict__ kin,
                                                   const float* __restrict__ cvec,
                                                   float* __restrict__ khat,
                                                   float* __restrict__ partial) {
    const int w    = threadIdx.x >> 6;          // wave id in block (0..3)
    const int lane = threadIdx.x & 63;
    const int wid  = (blockIdx.x << 2) + w;     // 0..32767, l-major
    const int l = wid >> 10, b = wid & 1023;
    const int row = b * L_ + l;

    __shared__ float kinS[4][M_];
    __shared__ int   pidxS[4][POOL];
    __shared__ float pexS[4][POOL];
    __shared__ int   sidxS[4][S_];
    __shared__ float svalS[4][S_];
    __shared__ int   pcntS[4];

    float* yo = y + (size_t)row * N_;
    const unsigned short* ya = (const unsigned short*)y + (size_t)row * 8192 + 4096;

    // stage kin (2 per lane) + init pool counter (in-wave LDS ops are ordered)
    kinS[w][lane]      = kin[(size_t)row * M_ + lane];
    kinS[w][lane + 64] = kin[(size_t)row * M_ + lane + 64];
    if (lane == 0) pcntS[w] = 0;

    // load 64 approx values (8 x 16B, coalesced: 64 lanes x 16B = 1KB/instr)
    ushort8_t u[8];
    #pragma unroll
    for (int j = 0; j < 8; ++j)
        u[j] = *reinterpret_cast<const ushort8_t*>(ya + j * 512 + lane * 8);
    float a[64];
    #pragma unroll
    for (int j = 0; j < 8; ++j)
        #pragma unroll
        for (int e = 0; e < 8; ++e)
            a[j * 8 + e] = fabsf(bf2f(u[j][e]));

    // fence: conversions above force the loads' waitcnt; then zero the high
    // half (exactly the bytes this wave just read). Drained before scatter.
    __builtin_amdgcn_sched_barrier(0);
    {
        const float4 z = {0.f, 0.f, 0.f, 0.f};
        #pragma unroll
        for (int j = 0; j < 8; ++j)
            *reinterpret_cast<float4*>(yo + 2048 + (j * 64 + lane) * 4) = z;
    }

    // wave max (no barrier)
    float mx = 0.0f;
    #pragma unroll
    for (int i = 0; i < 64; ++i) mx = fmaxf(mx, a[i]);
    #pragma unroll
    for (int o = 32; o > 0; o >>= 1) mx = fmaxf(mx, __shfl_xor(mx, o, 64));

    // bisect: count(a >= lo) >= 32 invariant; tighten until <= 40. shfl only.
    float lo = 0.0f, hi = mx;
    int cl = N_;
    for (int it = 0; it < 30 && cl > 40; ++it) {
        float t = 0.5f * (lo + hi);
        int c = 0;
        #pragma unroll
        for (int i = 0; i < 64; ++i) c += (a[i] >= t) ? 1 : 0;
        #pragma unroll
        for (int o = 32; o > 0; o >>= 1) c += __shfl_xor(c, o, 64);
        if (c >= S_) { lo = t; cl = c; } else { hi = t; }
    }

    // pool: approx >= lo - MARGIN (covers exact top-32; same bound as r9)
    const float th = lo - MARGIN;
    #pragma unroll
    for (int j = 0; j < 8; ++j)
        #pragma unroll
        for (int e = 0; e < 8; ++e)
            if (a[j * 8 + e] >= th) {
                int p = atomicAdd(&pcntS[w], 1);
                if (p < POOL) pidxS[w][p] = j * 512 + lane * 8 + e;
            }
    __asm__ __volatile__("s_waitcnt lgkmcnt(0)" ::: "memory");
    int c = pcntS[w]; c = c < POOL ? c : POOL;

    // exact recompute: ascending-m scalar fmaf chain (r4-verbatim order),
    // candidate e = lane and lane+64; We layer slice L2-resident (l-major).
    if (lane < c) {
        int n = pidxS[w][lane];
        const float* wp = We + ((size_t)l * N_ + n) * M_;
        float acc = -cvec[(size_t)l * N_ + n];
        #pragma unroll 8
        for (int m = 0; m < M_; ++m) acc = fmaf(wp[m], kinS[w][m], acc);
        pexS[w][lane] = acc;
    }
    if (lane + 64 < c) {
        int n = pidxS[w][lane + 64];
        const float* wp = We + ((size_t)l * N_ + n) * M_;
        float acc = -cvec[(size_t)l * N_ + n];
        #pragma unroll 8
        for (int m = 0; m < M_; ++m) acc = fmaf(wp[m], kinS[w][m], acc);
        pexS[w][lane + 64] = acc;
    }
    __asm__ __volatile__("s_waitcnt lgkmcnt(0)" ::: "memory");

    // exact rank (lowest-index tie-break); winners into LDS lists
    for (int e = lane; e < c; e += 64) {
        float ae = fabsf(pexS[w][e]);
        int   ne = pidxS[w][e];
        int rank = 0;
        for (int j = 0; j < c; ++j) {
            float aj = fabsf(pexS[w][j]);
            rank += ((aj > ae) || (aj == ae && pidxS[w][j] < ne)) ? 1 : 0;
        }
        if (rank < S_) {
            sidxS[w][rank] = ne;
            svalS[w][rank] = pexS[w][e];
        }
    }
    // drain this wave's high-half zero stores, and LDS winner writes
    __asm__ __volatile__("s_waitcnt vmcnt(0) lgkmcnt(0)" ::: "memory");

    // scatter the 32 winners (low half zeroed by zero_y_low kernel)
    if (lane < S_) yo[sidxS[w][lane]] = svalS[w][lane];

    // fused decode: 2 dims per lane; WdT rows coalesced (256B per half)
    const float* wt = WdT + (size_t)l * N_ * M_;
    float acc0 = 0.0f, acc1 = 0.0f;
    #pragma unroll 4
    for (int j = 0; j < S_; ++j) {
        float v = svalS[w][j];
        const float* wr = wt + (size_t)sidxS[w][j] * M_;
        acc0 = fmaf(v, wr[lane], acc0);
        acc1 = fmaf(v, wr[lane + 64], acc1);
    }
    khat[(size_t)row * M_ + lane]      = acc0;
    khat[(size_t)row * M_ + lane + 64] = acc1;
    float r0 = acc0 - kinS[w][lane];
    float r1 = acc1 - kinS[w][lane + 64];
    float s = r0 * r0 + r1 * r1;
    #pragma unroll
    for (int o = 32; o > 0; o >>= 1) s += __shfl_xor(s, o, 64);
    if (lane == 0) partial[row] = s;
}

// ---------------------------------------------------------------------------
// K4: deterministic reduction of 32768 partials -> loss
// ---------------------------------------------------------------------------
__global__ __launch_bounds__(256) void reduce_loss(const float* __restrict__ partial,
                                                   float* __restrict__ out_loss) {
    __shared__ float red[256];
    int tid = threadIdx.x;
    float s = 0.0f;
    for (int i = tid; i < ROWS; i += 256) s += partial[i];
    red[tid] = s;
    __syncthreads();
    for (int off = 128; off > 0; off >>= 1) {
        if (tid < off) red[tid] += red[tid + off];
        __syncthreads();
    }
    if (tid == 0) out_loss[0] = red[0] / (float)((size_t)B_ * L_ * M_);
}

// ---------------------------------------------------------------------------
extern "C" void kernel_launch(void* const* d_in, const int* in_sizes, int n_in,
                              void* d_out, int out_size, void* d_ws, size_t ws_size,
                              hipStream_t stream) {
    const float* kin = (const float*)d_in[0];   // [B][L][M]
    const float* We  = (const float*)d_in[1];   // [L][N][M]
    // d_in[2] = b_e (unused by reference encode())
    const float* Wd  = (const float*)d_in[3];   // [L][M][N]
    const float* bd  = (const float*)d_in[4];   // [L][M]
    // d_in[5] = s (==32, hardcoded)

    float* out   = (float*)d_out;
    float* loss  = out;                                   // [1]
    float* khat  = out + 1;                               // [B*L*M]
    float* y_out = out + 1 + (size_t)B_ * L_ * M_;        // [B*L*N]

    // workspace layout (region0 shared: Wbf during encode, WdT after)
    char* ws = (char*)d_ws;
    unsigned short* Wbf = (unsigned short*)ws;                   // 32 MiB (in 64 MiB region0)
    float*          WdT = (float*)ws;                            // 64 MiB (aliases Wbf)
    unsigned short* Abf = (unsigned short*)(ws + (64u << 20));   // 8 MiB
    float* cvec    = (float*)(ws + (80u << 20));                 // 512 KiB
    float* partial = (float*)(ws + (81u << 20));                 // 128 KiB

    // zero low halves of y early (pure streaming; approx lives in high halves)
    zero_y_low<<<2048, 256, 0, stream>>>(y_out);
    prep_w<<<dim3(N_ / 16, L_), 256, 0, stream>>>(We, bd, Wbf, cvec);
    prep_a<<<(B_ * L_ * M_) / 256, 256, 0, stream>>>(kin, Abf);
    encoder_mfma<<<dim3(N_ / 128, B_ / 128, L_), 256, 0, stream>>>(
        Abf, Wbf, cvec, (unsigned short*)y_out);
    // Wbf dead now; transpose overwrites region0 with WdT
    transpose_wd<<<dim3(N_ / 32, M_ / 32, L_), 256, 0, stream>>>(Wd, WdT);
    // wave-per-row fused backend
    topk_decode<<<ROWS / 4, 256, 0, stream>>>(y_out, We, WdT, kin, cvec, khat, partial);
    reduce_loss<<<1, 256, 0, stream>>>(partial, loss);
}

// Round 11
// 664.766 us; speedup vs baseline: 1.2363x; 1.1013x over previous
//
#include <hip/hip_runtime.h>
#include <hip/hip_bf16.h>

// Problem constants (fixed by the reference)
#define B_ 1024
#define L_ 32
#define M_ 128
#define N_ 4096
#define S_ 32
#define ROWS (B_ * L_)          // 32768 rows of length N_

typedef __attribute__((ext_vector_type(8))) short    short8_t;   // 8 bf16 (4 VGPR)
typedef __attribute__((ext_vector_type(8))) unsigned short ushort8_t;
typedef __attribute__((ext_vector_type(4))) float    f32x4;

__device__ __forceinline__ unsigned short f2bf(float x) {  // RNE bf16
    unsigned u = __float_as_uint(x);
    unsigned r = (u + 0x7FFFu + ((u >> 16) & 1u)) >> 16;
    return (unsigned short)r;
}
__device__ __forceinline__ float bf2f(unsigned short h) {
    return __uint_as_float((unsigned)h << 16);
}

// ---------------------------------------------------------------------------
// K0: transpose W_d [L][M][N] -> W_dT [L][N][M] (runs AFTER encoder; WdT
// aliases the Wbf region)
// ---------------------------------------------------------------------------
__global__ __launch_bounds__(256) void transpose_wd(const float* __restrict__ Wd,
                                                    float* __restrict__ WdT) {
    __shared__ float t[32][33];
    int l = blockIdx.z;
    int n0 = blockIdx.x * 32, m0 = blockIdx.y * 32;
    int tx = threadIdx.x & 31, ty = threadIdx.x >> 5;
    const float* src = Wd + (size_t)l * M_ * N_;
    for (int i = ty; i < 32; i += 8)
        t[i][tx] = src[(size_t)(m0 + i) * N_ + n0 + tx];
    __syncthreads();
    float* dst = WdT + (size_t)l * N_ * M_;
    for (int i = ty; i < 32; i += 8)
        dst[(size_t)(n0 + i) * M_ + m0 + tx] = t[tx][i];
}

// ---------------------------------------------------------------------------
// Z: zero the LOW 8KB half of every y row slot (pure streaming, full BW).
// The encoder writes approx into the HIGH half, so this is safe to run first.
// ---------------------------------------------------------------------------
__global__ __launch_bounds__(256) void zero_y_low(float* __restrict__ y) {
    const float4 z = {0.f, 0.f, 0.f, 0.f};
    int idx = blockIdx.x * 256 + threadIdx.x;
    for (int i = idx; i < ROWS * 512; i += 2048 * 256) {
        int row = i >> 9, slot = i & 511;
        reinterpret_cast<float4*>(y + (size_t)row * N_)[slot] = z;
    }
}

// ---------------------------------------------------------------------------
// P1: prep W (fused bias_dot): Wbf[l][n][128] = bf16(We row); cvec = b_d . We_n
// ---------------------------------------------------------------------------
__global__ __launch_bounds__(256) void prep_w(const float* __restrict__ We,
                                              const float* __restrict__ bd,
                                              unsigned short* __restrict__ Wbf,
                                              float* __restrict__ cvec) {
    int l = blockIdx.y;
    int tid = threadIdx.x;
    int nl = tid >> 4, t = tid & 15;
    int n = blockIdx.x * 16 + nl;
    const float* w = We + ((size_t)l * N_ + n) * M_ + t * 8;
    const float* b = bd + l * M_ + t * 8;
    float4 w0 = *(const float4*)(w), w1 = *(const float4*)(w + 4);
    float4 b0 = *(const float4*)(b), b1 = *(const float4*)(b + 4);
    ushort8_t o;
    o[0] = f2bf(w0.x); o[1] = f2bf(w0.y); o[2] = f2bf(w0.z); o[3] = f2bf(w0.w);
    o[4] = f2bf(w1.x); o[5] = f2bf(w1.y); o[6] = f2bf(w1.z); o[7] = f2bf(w1.w);
    *reinterpret_cast<ushort8_t*>(Wbf + ((size_t)l * N_ + n) * 128 + t * 8) = o;
    float s = w0.x*b0.x + w0.y*b0.y + w0.z*b0.z + w0.w*b0.w
            + w1.x*b1.x + w1.y*b1.y + w1.z*b1.z + w1.w*b1.w;
    #pragma unroll
    for (int oo = 8; oo > 0; oo >>= 1) s += __shfl_xor(s, oo, 64);
    if (t == 0) cvec[(size_t)l * N_ + n] = s;
}

// P2: prep A: Abf[l][b][128] = bf16(kin[b][l][:])
__global__ __launch_bounds__(256) void prep_a(const float* __restrict__ kin,
                                              unsigned short* __restrict__ Abf) {
    int g = blockIdx.x * 256 + threadIdx.x;       // over B*L*M
    int b = g >> 12, l = (g >> 7) & 31, m = g & 127;
    Abf[(((size_t)l * B_ + b) << 7) + m] = f2bf(kin[g]);
}

// ---------------------------------------------------------------------------
// K1: encoder approx GEMM via MFMA bf16, single term (K=128, 4 BK=32 steps).
// Epilogue: accumulators -> padded LDS tile (conflict-free) -> COALESCED 16B
// stores into the HIGH 8KB half of each row's 16KB y slot.
// LDS is a union: staging (As 8KB + Bs 8KB) during K-loop, C-tile (34.8KB)
// after a barrier.
// ---------------------------------------------------------------------------
__device__ __forceinline__ int swz(int row) { return (row & 3) ^ ((row >> 2) & 3); }

#define CP 136   // C-tile row pitch in shorts (272B = 17x16B: 16B-aligned rows, conflict-free)

__global__ __launch_bounds__(256) void encoder_mfma(const unsigned short* __restrict__ Abf,
                                                    const unsigned short* __restrict__ Wbf,
                                                    const float* __restrict__ cvec,
                                                    unsigned short* __restrict__ y16) {
    const int l   = blockIdx.z;
    const int bn0 = blockIdx.x * 128;
    const int bm0 = blockIdx.y * 128;
    __shared__ __align__(16) unsigned short smem[128 * CP];   // 34.8KB
    unsigned short* As = smem;                                 // 8KB during K-loop
    unsigned short* Bs = smem + 128 * 32;                      // 8KB during K-loop
    const int tid  = threadIdx.x;
    const int lane = tid & 63, wave = tid >> 6;
    const int wr = wave >> 1, wc = wave & 1;

    const unsigned short* Ab = Abf + (((size_t)l * B_ + bm0) << 7);
    const unsigned short* Wb = Wbf + (((size_t)l * N_ + bn0) << 7);

    auto stage = [&](int k0) {
        #pragma unroll
        for (int i = 0; i < 2; ++i) {
            int p   = i * 256 + tid;
            int row = p >> 2;
            int lc  = (p & 3) ^ swz(row);
            const unsigned short* g = Ab + ((size_t)row << 7) + k0 + lc * 8;
            unsigned dst = (unsigned)((i * 256 + (tid & ~63)) * 16);
            __builtin_amdgcn_global_load_lds(
                (const __attribute__((address_space(1))) void*)g,
                (__attribute__((address_space(3))) void*)((char*)As + dst), 16, 0, 0);
        }
        #pragma unroll
        for (int i = 0; i < 2; ++i) {
            int p   = i * 256 + tid;
            int row = p >> 2;
            int lc  = (p & 3) ^ swz(row);
            const unsigned short* g = Wb + ((size_t)row << 7) + k0 + lc * 8;
            unsigned dst = (unsigned)((i * 256 + (tid & ~63)) * 16);
            __builtin_amdgcn_global_load_lds(
                (const __attribute__((address_space(1))) void*)g,
                (__attribute__((address_space(3))) void*)((char*)Bs + dst), 16, 0, 0);
        }
    };

    f32x4 acc[4][4];
    #pragma unroll
    for (int i = 0; i < 4; ++i)
        #pragma unroll
        for (int j = 0; j < 4; ++j) acc[i][j] = (f32x4){0.f, 0.f, 0.f, 0.f};

    stage(0);
    __syncthreads();

    #pragma unroll
    for (int t = 0; t < 4; ++t) {
        short8_t aF[4], bF[4];
        const int kg = lane >> 4;
        #pragma unroll
        for (int mt = 0; mt < 4; ++mt) {
            int row = wr * 64 + mt * 16 + (lane & 15);
            int pc  = kg ^ swz(row);
            aF[mt] = *reinterpret_cast<const short8_t*>(As + row * 32 + pc * 8);
        }
        #pragma unroll
        for (int nt = 0; nt < 4; ++nt) {
            int row = wc * 64 + nt * 16 + (lane & 15);
            int pc  = kg ^ swz(row);
            bF[nt] = *reinterpret_cast<const short8_t*>(Bs + row * 32 + pc * 8);
        }
        #pragma unroll
        for (int mt = 0; mt < 4; ++mt)
            #pragma unroll
            for (int nt = 0; nt < 4; ++nt)
                acc[mt][nt] = __builtin_amdgcn_mfma_f32_16x16x32_bf16(
                    aF[mt], bF[nt], acc[mt][nt], 0, 0, 0);

        if (t < 3) {
            __syncthreads();
            stage((t + 1) * 32);
            __syncthreads();
        }
    }

    // staging dead; repurpose LDS as C tile
    __syncthreads();

    // bf16 C values -> LDS (conflict-free: row stride 272B ≡ 4 dwords mod 32 banks)
    #pragma unroll
    for (int nt = 0; nt < 4; ++nt) {
        int nl = wc * 64 + nt * 16 + (lane & 15);
        float cj = cvec[(size_t)l * N_ + bn0 + nl];
        #pragma unroll
        for (int mt = 0; mt < 4; ++mt) {
            #pragma unroll
            for (int j = 0; j < 4; ++j) {
                int rl = wr * 64 + mt * 16 + (lane >> 4) * 4 + j;
                smem[rl * CP + nl] = f2bf(acc[mt][nt][j] - cj);
            }
        }
    }
    __syncthreads();

    // coalesced store: 2048 16B-chunks; 16 threads per row -> 256B contiguous
    #pragma unroll
    for (int i = 0; i < 8; ++i) {
        int chunk = i * 256 + tid;
        int r = chunk >> 4, cch = chunk & 15;
        ushort8_t v = *reinterpret_cast<const ushort8_t*>(smem + r * CP + cch * 8);
        unsigned short* dst = y16 + ((size_t)((bm0 + r) * L_ + l)) * 8192 + 4096 + bn0 + cch * 8;
        *reinterpret_cast<ushort8_t*>(dst) = v;
    }
}

// ---------------------------------------------------------------------------
// K2 (wave-per-row SELECTOR+DECODER, zero block barriers, NO y writes):
// one 64-lane wave owns a row: 64 approx in VGPRs, shfl bisect, pool via
// wave-local LDS atomics, r4-verbatim ascending-m exact recompute, exact rank
// -> cidx/cval; fused khat decode + residual. L-major wave order for L2.
// ---------------------------------------------------------------------------
#define POOL 96
#define MARGIN 1.2e-3f

__global__ __launch_bounds__(256) void topk_decode(const float* __restrict__ y,
                                                   const float* __restrict__ We,
                                                   const float* __restrict__ WdT,
                                                   const float* __restrict__ kin,
                                                   const float* __restrict__ cvec,
                                                   int* __restrict__ cidx,
                                                   float* __restrict__ cval,
                                                   float* __restrict__ khat,
                                                   float* __restrict__ partial) {
    const int w    = threadIdx.x >> 6;          // wave id in block (0..3)
    const int lane = threadIdx.x & 63;
    const int wid  = (blockIdx.x << 2) + w;     // 0..32767, l-major
    const int l = wid >> 10, b = wid & 1023;
    const int row = b * L_ + l;

    __shared__ float kinS[4][M_];
    __shared__ int   pidxS[4][POOL];
    __shared__ float pexS[4][POOL];
    __shared__ int   sidxS[4][S_];
    __shared__ float svalS[4][S_];
    __shared__ int   pcntS[4];

    const unsigned short* ya = (const unsigned short*)y + (size_t)row * 8192 + 4096;

    kinS[w][lane]      = kin[(size_t)row * M_ + lane];
    kinS[w][lane + 64] = kin[(size_t)row * M_ + lane + 64];
    if (lane == 0) pcntS[w] = 0;

    // load 64 approx values (8 x 16B, coalesced)
    ushort8_t u[8];
    #pragma unroll
    for (int j = 0; j < 8; ++j)
        u[j] = *reinterpret_cast<const ushort8_t*>(ya + j * 512 + lane * 8);
    float a[64];
    #pragma unroll
    for (int j = 0; j < 8; ++j)
        #pragma unroll
        for (int e = 0; e < 8; ++e)
            a[j * 8 + e] = fabsf(bf2f(u[j][e]));

    // wave max
    float mx = 0.0f;
    #pragma unroll
    for (int i = 0; i < 64; ++i) mx = fmaxf(mx, a[i]);
    #pragma unroll
    for (int o = 32; o > 0; o >>= 1) mx = fmaxf(mx, __shfl_xor(mx, o, 64));

    // bisect: count(a >= lo) >= 32 invariant; tighten until <= 40. shfl only.
    float lo = 0.0f, hi = mx;
    int cl = N_;
    for (int it = 0; it < 30 && cl > 40; ++it) {
        float t = 0.5f * (lo + hi);
        int c = 0;
        #pragma unroll
        for (int i = 0; i < 64; ++i) c += (a[i] >= t) ? 1 : 0;
        #pragma unroll
        for (int o = 32; o > 0; o >>= 1) c += __shfl_xor(c, o, 64);
        if (c >= S_) { lo = t; cl = c; } else { hi = t; }
    }

    // pool: approx >= lo - MARGIN (covers exact top-32; bound proven r9)
    const float th = lo - MARGIN;
    #pragma unroll
    for (int j = 0; j < 8; ++j)
        #pragma unroll
        for (int e = 0; e < 8; ++e)
            if (a[j * 8 + e] >= th) {
                int p = atomicAdd(&pcntS[w], 1);
                if (p < POOL) pidxS[w][p] = j * 512 + lane * 8 + e;
            }
    __asm__ __volatile__("s_waitcnt lgkmcnt(0)" ::: "memory");
    int c = pcntS[w]; c = c < POOL ? c : POOL;

    // exact recompute: ascending-m scalar fmaf chain (r4-verbatim order)
    if (lane < c) {
        int n = pidxS[w][lane];
        const float* wp = We + ((size_t)l * N_ + n) * M_;
        float acc = -cvec[(size_t)l * N_ + n];
        #pragma unroll 8
        for (int m = 0; m < M_; ++m) acc = fmaf(wp[m], kinS[w][m], acc);
        pexS[w][lane] = acc;
    }
    if (lane + 64 < c) {
        int n = pidxS[w][lane + 64];
        const float* wp = We + ((size_t)l * N_ + n) * M_;
        float acc = -cvec[(size_t)l * N_ + n];
        #pragma unroll 8
        for (int m = 0; m < M_; ++m) acc = fmaf(wp[m], kinS[w][m], acc);
        pexS[w][lane + 64] = acc;
    }
    __asm__ __volatile__("s_waitcnt lgkmcnt(0)" ::: "memory");

    // exact rank (lowest-index tie-break); winners into LDS lists
    for (int e = lane; e < c; e += 64) {
        float ae = fabsf(pexS[w][e]);
        int   ne = pidxS[w][e];
        int rank = 0;
        for (int j = 0; j < c; ++j) {
            float aj = fabsf(pexS[w][j]);
            rank += ((aj > ae) || (aj == ae && pidxS[w][j] < ne)) ? 1 : 0;
        }
        if (rank < S_) {
            sidxS[w][rank] = ne;
            svalS[w][rank] = pexS[w][e];
        }
    }
    __asm__ __volatile__("s_waitcnt lgkmcnt(0)" ::: "memory");

    // emit compact winner lists
    if (lane < S_) {
        cidx[(size_t)row * S_ + lane] = sidxS[w][lane];
        cval[(size_t)row * S_ + lane] = svalS[w][lane];
    }

    // fused decode: 2 dims per lane; WdT rows L2-resident (l-major)
    const float* wt = WdT + (size_t)l * N_ * M_;
    float acc0 = 0.0f, acc1 = 0.0f;
    #pragma unroll 4
    for (int j = 0; j < S_; ++j) {
        float v = svalS[w][j];
        const float* wrp = wt + (size_t)sidxS[w][j] * M_;
        acc0 = fmaf(v, wrp[lane], acc0);
        acc1 = fmaf(v, wrp[lane + 64], acc1);
    }
    khat[(size_t)row * M_ + lane]      = acc0;
    khat[(size_t)row * M_ + lane + 64] = acc1;
    float r0 = acc0 - kinS[w][lane];
    float r1 = acc1 - kinS[w][lane + 64];
    float s = r0 * r0 + r1 * r1;
    #pragma unroll
    for (int o = 32; o > 0; o >>= 1) s += __shfl_xor(s, o, 64);
    if (lane == 0) partial[row] = s;
}

// ---------------------------------------------------------------------------
// K3: STREAMING finisher: zero the HIGH 8KB half (overwrites the approx) and
// scatter the 32 winners. Block per row; one barrier (drains the zero stores
// before winners land, since winner n may fall in the high half).
// ---------------------------------------------------------------------------
__global__ __launch_bounds__(256) void scatter_zero_high(float* __restrict__ y,
                                                         const int* __restrict__ cidx,
                                                         const float* __restrict__ cval) {
    const int bid = blockIdx.x;
    const int l = bid >> 10, b = bid & 1023;    // l-major
    const int row = b * L_ + l;
    const int tid = threadIdx.x;
    __shared__ int   sidx[S_];
    __shared__ float sval[S_];
    if (tid < S_) { sidx[tid] = cidx[(size_t)row * S_ + tid]; sval[tid] = cval[(size_t)row * S_ + tid]; }

    float* yo = y + (size_t)row * N_;
    const float4 z = {0.f, 0.f, 0.f, 0.f};
    #pragma unroll
    for (int i = 0; i < 2; ++i)
        reinterpret_cast<float4*>(yo + 2048)[i * 256 + tid] = z;
    __syncthreads();   // drains zero stores; sidx/sval visible
    if (tid < S_) yo[sidx[tid]] = sval[tid];
}

// ---------------------------------------------------------------------------
// K4: deterministic reduction of 32768 partials -> loss
// ---------------------------------------------------------------------------
__global__ __launch_bounds__(256) void reduce_loss(const float* __restrict__ partial,
                                                   float* __restrict__ out_loss) {
    __shared__ float red[256];
    int tid = threadIdx.x;
    float s = 0.0f;
    for (int i = tid; i < ROWS; i += 256) s += partial[i];
    red[tid] = s;
    __syncthreads();
    for (int off = 128; off > 0; off >>= 1) {
        if (tid < off) red[tid] += red[tid + off];
        __syncthreads();
    }
    if (tid == 0) out_loss[0] = red[0] / (float)((size_t)B_ * L_ * M_);
}

// ---------------------------------------------------------------------------
extern "C" void kernel_launch(void* const* d_in, const int* in_sizes, int n_in,
                              void* d_out, int out_size, void* d_ws, size_t ws_size,
                              hipStream_t stream) {
    const float* kin = (const float*)d_in[0];   // [B][L][M]
    const float* We  = (const float*)d_in[1];   // [L][N][M]
    // d_in[2] = b_e (unused by reference encode())
    const float* Wd  = (const float*)d_in[3];   // [L][M][N]
    const float* bd  = (const float*)d_in[4];   // [L][M]
    // d_in[5] = s (==32, hardcoded)

    float* out   = (float*)d_out;
    float* loss  = out;                                   // [1]
    float* khat  = out + 1;                               // [B*L*M]
    float* y_out = out + 1 + (size_t)B_ * L_ * M_;        // [B*L*N]

    // workspace layout (region0 shared: Wbf during encode, WdT after)
    char* ws = (char*)d_ws;
    unsigned short* Wbf = (unsigned short*)ws;                   // 32 MiB (in 64 MiB region0)
    float*          WdT = (float*)ws;                            // 64 MiB (aliases Wbf)
    unsigned short* Abf = (unsigned short*)(ws + (64u << 20));   // 8 MiB
    int*   cidx    = (int*)  (ws + (72u << 20));                 // 4 MiB
    float* cval    = (float*)(ws + (76u << 20));                 // 4 MiB
    float* cvec    = (float*)(ws + (80u << 20));                 // 512 KiB
    float* partial = (float*)(ws + (81u << 20));                 // 128 KiB

    // zero low halves of y early (approx lives in high halves)
    zero_y_low<<<2048, 256, 0, stream>>>(y_out);
    prep_w<<<dim3(N_ / 16, L_), 256, 0, stream>>>(We, bd, Wbf, cvec);
    prep_a<<<(B_ * L_ * M_) / 256, 256, 0, stream>>>(kin, Abf);
    encoder_mfma<<<dim3(N_ / 128, B_ / 128, L_), 256, 0, stream>>>(
        Abf, Wbf, cvec, (unsigned short*)y_out);
    // Wbf dead now; transpose overwrites region0 with WdT
    transpose_wd<<<dim3(N_ / 32, M_ / 32, L_), 256, 0, stream>>>(Wd, WdT);
    // wave-per-row selector + decoder (no y writes)
    topk_decode<<<ROWS / 4, 256, 0, stream>>>(y_out, We, WdT, kin, cvec,
                                              cidx, cval, khat, partial);
    // streaming finisher: zero high halves + scatter winners
    scatter_zero_high<<<ROWS, 256, 0, stream>>>(y_out, cidx, cval);
    reduce_loss<<<1, 256, 0, stream>>>(partial, loss);
}

// Round 12
// 600.757 us; speedup vs baseline: 1.3680x; 1.1065x over previous
//
#include <hip/hip_runtime.h>
#include <hip/hip_bf16.h>

// Problem constants (fixed by the reference)
#define B_ 1024
#define L_ 32
#define M_ 128
#define N_ 4096
#define S_ 32
#define ROWS (B_ * L_)          // 32768 rows of length N_

typedef __attribute__((ext_vector_type(8))) short    short8_t;   // 8 bf16 (4 VGPR)
typedef __attribute__((ext_vector_type(8))) unsigned short ushort8_t;
typedef __attribute__((ext_vector_type(4))) float    f32x4;

__device__ __forceinline__ unsigned short f2bf(float x) {  // RNE bf16
    unsigned u = __float_as_uint(x);
    unsigned r = (u + 0x7FFFu + ((u >> 16) & 1u)) >> 16;
    return (unsigned short)r;
}
__device__ __forceinline__ float bf2f(unsigned short h) {
    return __uint_as_float((unsigned)h << 16);
}

// ---------------------------------------------------------------------------
// K0: transpose W_d [L][M][N] -> W_dT [L][N][M] (runs AFTER encoder; WdT
// aliases the Wbf region)
// ---------------------------------------------------------------------------
__global__ __launch_bounds__(256) void transpose_wd(const float* __restrict__ Wd,
                                                    float* __restrict__ WdT) {
    __shared__ float t[32][33];
    int l = blockIdx.z;
    int n0 = blockIdx.x * 32, m0 = blockIdx.y * 32;
    int tx = threadIdx.x & 31, ty = threadIdx.x >> 5;
    const float* src = Wd + (size_t)l * M_ * N_;
    for (int i = ty; i < 32; i += 8)
        t[i][tx] = src[(size_t)(m0 + i) * N_ + n0 + tx];
    __syncthreads();
    float* dst = WdT + (size_t)l * N_ * M_;
    for (int i = ty; i < 32; i += 8)
        dst[(size_t)(n0 + i) * M_ + m0 + tx] = t[tx][i];
}

// ---------------------------------------------------------------------------
// Z1: zero the LOW 8KB half of every y row slot (pure streaming, full BW).
// Runs FIRST; the encoder writes approx into the HIGH half only, and
// topk_decode scatters low-half winners directly onto these zeros.
// ---------------------------------------------------------------------------
__global__ __launch_bounds__(256) void zero_y_low(float* __restrict__ y) {
    const float4 z = {0.f, 0.f, 0.f, 0.f};
    int idx = blockIdx.x * 256 + threadIdx.x;
    for (int i = idx; i < ROWS * 512; i += 2048 * 256) {
        int row = i >> 9, slot = i & 511;
        reinterpret_cast<float4*>(y + (size_t)row * N_)[slot] = z;
    }
}

// Z2: zero the HIGH 8KB half (overwrites the approx). Pure streaming.
__global__ __launch_bounds__(256) void zero_y_high(float* __restrict__ y) {
    const float4 z = {0.f, 0.f, 0.f, 0.f};
    int idx = blockIdx.x * 256 + threadIdx.x;
    for (int i = idx; i < ROWS * 512; i += 2048 * 256) {
        int row = i >> 9, slot = i & 511;
        reinterpret_cast<float4*>(y + (size_t)row * N_ + 2048)[slot] = z;
    }
}

// Z3: scatter high-half winners (n >= 2048) after zero_y_high. Tiny.
__global__ __launch_bounds__(256) void scatter_high(float* __restrict__ y,
                                                    const int* __restrict__ cidx,
                                                    const float* __restrict__ cval) {
    int g = blockIdx.x * 256 + threadIdx.x;       // over ROWS*S
    int row = g >> 5;
    int n = cidx[g];
    if (n >= 2048) y[(size_t)row * N_ + n] = cval[g];
}

// ---------------------------------------------------------------------------
// P1: prep W (fused bias_dot): Wbf[l][n][128] = bf16(We row); cvec = b_d . We_n
// ---------------------------------------------------------------------------
__global__ __launch_bounds__(256) void prep_w(const float* __restrict__ We,
                                              const float* __restrict__ bd,
                                              unsigned short* __restrict__ Wbf,
                                              float* __restrict__ cvec) {
    int l = blockIdx.y;
    int tid = threadIdx.x;
    int nl = tid >> 4, t = tid & 15;
    int n = blockIdx.x * 16 + nl;
    const float* w = We + ((size_t)l * N_ + n) * M_ + t * 8;
    const float* b = bd + l * M_ + t * 8;
    float4 w0 = *(const float4*)(w), w1 = *(const float4*)(w + 4);
    float4 b0 = *(const float4*)(b), b1 = *(const float4*)(b + 4);
    ushort8_t o;
    o[0] = f2bf(w0.x); o[1] = f2bf(w0.y); o[2] = f2bf(w0.z); o[3] = f2bf(w0.w);
    o[4] = f2bf(w1.x); o[5] = f2bf(w1.y); o[6] = f2bf(w1.z); o[7] = f2bf(w1.w);
    *reinterpret_cast<ushort8_t*>(Wbf + ((size_t)l * N_ + n) * 128 + t * 8) = o;
    float s = w0.x*b0.x + w0.y*b0.y + w0.z*b0.z + w0.w*b0.w
            + w1.x*b1.x + w1.y*b1.y + w1.z*b1.z + w1.w*b1.w;
    #pragma unroll
    for (int oo = 8; oo > 0; oo >>= 1) s += __shfl_xor(s, oo, 64);
    if (t == 0) cvec[(size_t)l * N_ + n] = s;
}

// P2: prep A: Abf[l][b][128] = bf16(kin[b][l][:])
__global__ __launch_bounds__(256) void prep_a(const float* __restrict__ kin,
                                              unsigned short* __restrict__ Abf) {
    int g = blockIdx.x * 256 + threadIdx.x;       // over B*L*M
    int b = g >> 12, l = (g >> 7) & 31, m = g & 127;
    Abf[(((size_t)l * B_ + b) << 7) + m] = f2bf(kin[g]);
}

// ---------------------------------------------------------------------------
// K1: encoder approx GEMM via MFMA bf16, single term (K=128, 4 BK=32 steps).
// Epilogue: padded-LDS re-tile -> coalesced 16B stores to the HIGH half.
// ---------------------------------------------------------------------------
__device__ __forceinline__ int swz(int row) { return (row & 3) ^ ((row >> 2) & 3); }

#define CP 136   // C-tile row pitch in shorts

__global__ __launch_bounds__(256) void encoder_mfma(const unsigned short* __restrict__ Abf,
                                                    const unsigned short* __restrict__ Wbf,
                                                    const float* __restrict__ cvec,
                                                    unsigned short* __restrict__ y16) {
    const int l   = blockIdx.z;
    const int bn0 = blockIdx.x * 128;
    const int bm0 = blockIdx.y * 128;
    __shared__ __align__(16) unsigned short smem[128 * CP];   // 34.8KB
    unsigned short* As = smem;
    unsigned short* Bs = smem + 128 * 32;
    const int tid  = threadIdx.x;
    const int lane = tid & 63, wave = tid >> 6;
    const int wr = wave >> 1, wc = wave & 1;

    const unsigned short* Ab = Abf + (((size_t)l * B_ + bm0) << 7);
    const unsigned short* Wb = Wbf + (((size_t)l * N_ + bn0) << 7);

    auto stage = [&](int k0) {
        #pragma unroll
        for (int i = 0; i < 2; ++i) {
            int p   = i * 256 + tid;
            int row = p >> 2;
            int lc  = (p & 3) ^ swz(row);
            const unsigned short* g = Ab + ((size_t)row << 7) + k0 + lc * 8;
            unsigned dst = (unsigned)((i * 256 + (tid & ~63)) * 16);
            __builtin_amdgcn_global_load_lds(
                (const __attribute__((address_space(1))) void*)g,
                (__attribute__((address_space(3))) void*)((char*)As + dst), 16, 0, 0);
        }
        #pragma unroll
        for (int i = 0; i < 2; ++i) {
            int p   = i * 256 + tid;
            int row = p >> 2;
            int lc  = (p & 3) ^ swz(row);
            const unsigned short* g = Wb + ((size_t)row << 7) + k0 + lc * 8;
            unsigned dst = (unsigned)((i * 256 + (tid & ~63)) * 16);
            __builtin_amdgcn_global_load_lds(
                (const __attribute__((address_space(1))) void*)g,
                (__attribute__((address_space(3))) void*)((char*)Bs + dst), 16, 0, 0);
        }
    };

    f32x4 acc[4][4];
    #pragma unroll
    for (int i = 0; i < 4; ++i)
        #pragma unroll
        for (int j = 0; j < 4; ++j) acc[i][j] = (f32x4){0.f, 0.f, 0.f, 0.f};

    stage(0);
    __syncthreads();

    #pragma unroll
    for (int t = 0; t < 4; ++t) {
        short8_t aF[4], bF[4];
        const int kg = lane >> 4;
        #pragma unroll
        for (int mt = 0; mt < 4; ++mt) {
            int row = wr * 64 + mt * 16 + (lane & 15);
            int pc  = kg ^ swz(row);
            aF[mt] = *reinterpret_cast<const short8_t*>(As + row * 32 + pc * 8);
        }
        #pragma unroll
        for (int nt = 0; nt < 4; ++nt) {
            int row = wc * 64 + nt * 16 + (lane & 15);
            int pc  = kg ^ swz(row);
            bF[nt] = *reinterpret_cast<const short8_t*>(Bs + row * 32 + pc * 8);
        }
        #pragma unroll
        for (int mt = 0; mt < 4; ++mt)
            #pragma unroll
            for (int nt = 0; nt < 4; ++nt)
                acc[mt][nt] = __builtin_amdgcn_mfma_f32_16x16x32_bf16(
                    aF[mt], bF[nt], acc[mt][nt], 0, 0, 0);

        if (t < 3) {
            __syncthreads();
            stage((t + 1) * 32);
            __syncthreads();
        }
    }

    __syncthreads();   // staging dead; repurpose LDS as C tile

    #pragma unroll
    for (int nt = 0; nt < 4; ++nt) {
        int nl = wc * 64 + nt * 16 + (lane & 15);
        float cj = cvec[(size_t)l * N_ + bn0 + nl];
        #pragma unroll
        for (int mt = 0; mt < 4; ++mt) {
            #pragma unroll
            for (int j = 0; j < 4; ++j) {
                int rl = wr * 64 + mt * 16 + (lane >> 4) * 4 + j;
                smem[rl * CP + nl] = f2bf(acc[mt][nt][j] - cj);
            }
        }
    }
    __syncthreads();

    #pragma unroll
    for (int i = 0; i < 8; ++i) {
        int chunk = i * 256 + tid;
        int r = chunk >> 4, cch = chunk & 15;
        ushort8_t v = *reinterpret_cast<const ushort8_t*>(smem + r * CP + cch * 8);
        unsigned short* dst = y16 + ((size_t)((bm0 + r) * L_ + l)) * 8192 + 4096 + bn0 + cch * 8;
        *reinterpret_cast<ushort8_t*>(dst) = v;
    }
}

// ---------------------------------------------------------------------------
// K2 (wave-per-row selector+decoder, zero block barriers):
// shfl bisect on approx, pool via wave-local LDS atomics, float4-vectorized
// exact recompute (STRICT ascending-m fmaf order -- bit-identical to r4),
// exact rank -> cidx/cval + DIRECT low-half scatter; fused khat decode +
// residual. L-major wave order for L2 locality on We/WdT.
// ---------------------------------------------------------------------------
#define POOL 96
#define MARGIN 1.2e-3f

__global__ __launch_bounds__(256) void topk_decode(float* __restrict__ y,
                                                   const float* __restrict__ We,
                                                   const float* __restrict__ WdT,
                                                   const float* __restrict__ kin,
                                                   const float* __restrict__ cvec,
                                                   int* __restrict__ cidx,
                                                   float* __restrict__ cval,
                                                   float* __restrict__ khat,
                                                   float* __restrict__ partial) {
    const int w    = threadIdx.x >> 6;          // wave id in block (0..3)
    const int lane = threadIdx.x & 63;
    const int wid  = (blockIdx.x << 2) + w;     // 0..32767, l-major
    const int l = wid >> 10, b = wid & 1023;
    const int row = b * L_ + l;

    __shared__ __align__(16) float kinS[4][M_];
    __shared__ int   pidxS[4][POOL];
    __shared__ float pexS[4][POOL];
    __shared__ int   sidxS[4][S_];
    __shared__ float svalS[4][S_];
    __shared__ int   pcntS[4];

    float* yo = y + (size_t)row * N_;
    const unsigned short* ya = (const unsigned short*)y + (size_t)row * 8192 + 4096;

    kinS[w][lane]      = kin[(size_t)row * M_ + lane];
    kinS[w][lane + 64] = kin[(size_t)row * M_ + lane + 64];
    if (lane == 0) pcntS[w] = 0;

    // load 64 approx values (8 x 16B, coalesced)
    ushort8_t u[8];
    #pragma unroll
    for (int j = 0; j < 8; ++j)
        u[j] = *reinterpret_cast<const ushort8_t*>(ya + j * 512 + lane * 8);
    float a[64];
    #pragma unroll
    for (int j = 0; j < 8; ++j)
        #pragma unroll
        for (int e = 0; e < 8; ++e)
            a[j * 8 + e] = fabsf(bf2f(u[j][e]));

    // wave max
    float mx = 0.0f;
    #pragma unroll
    for (int i = 0; i < 64; ++i) mx = fmaxf(mx, a[i]);
    #pragma unroll
    for (int o = 32; o > 0; o >>= 1) mx = fmaxf(mx, __shfl_xor(mx, o, 64));

    // bisect: count(a >= lo) >= 32 invariant; tighten until <= 40. shfl only.
    float lo = 0.0f, hi = mx;
    int cl = N_;
    for (int it = 0; it < 30 && cl > 40; ++it) {
        float t = 0.5f * (lo + hi);
        int c = 0;
        #pragma unroll
        for (int i = 0; i < 64; ++i) c += (a[i] >= t) ? 1 : 0;
        #pragma unroll
        for (int o = 32; o > 0; o >>= 1) c += __shfl_xor(c, o, 64);
        if (c >= S_) { lo = t; cl = c; } else { hi = t; }
    }

    // pool: approx >= lo - MARGIN (covers exact top-32; bound proven r9-r11)
    const float th = lo - MARGIN;
    #pragma unroll
    for (int j = 0; j < 8; ++j)
        #pragma unroll
        for (int e = 0; e < 8; ++e)
            if (a[j * 8 + e] >= th) {
                int p = atomicAdd(&pcntS[w], 1);
                if (p < POOL) pidxS[w][p] = j * 512 + lane * 8 + e;
            }
    __asm__ __volatile__("s_waitcnt lgkmcnt(0)" ::: "memory");
    int c = pcntS[w]; c = c < POOL ? c : POOL;

    // exact recompute: STRICT ascending-m fmaf chain (bit-identical to r4);
    // float4 loads (We global, kin LDS) then 4 in-order scalar fmafs.
    if (lane < c) {
        int n = pidxS[w][lane];
        const float4* wp4 = reinterpret_cast<const float4*>(We + ((size_t)l * N_ + n) * M_);
        const float4* kp4 = reinterpret_cast<const float4*>(kinS[w]);
        float acc = -cvec[(size_t)l * N_ + n];
        #pragma unroll 8
        for (int m4 = 0; m4 < 32; ++m4) {
            float4 wv = wp4[m4], kv = kp4[m4];
            acc = fmaf(wv.x, kv.x, acc);
            acc = fmaf(wv.y, kv.y, acc);
            acc = fmaf(wv.z, kv.z, acc);
            acc = fmaf(wv.w, kv.w, acc);
        }
        pexS[w][lane] = acc;
    }
    if (lane + 64 < c) {
        int n = pidxS[w][lane + 64];
        const float4* wp4 = reinterpret_cast<const float4*>(We + ((size_t)l * N_ + n) * M_);
        const float4* kp4 = reinterpret_cast<const float4*>(kinS[w]);
        float acc = -cvec[(size_t)l * N_ + n];
        #pragma unroll 8
        for (int m4 = 0; m4 < 32; ++m4) {
            float4 wv = wp4[m4], kv = kp4[m4];
            acc = fmaf(wv.x, kv.x, acc);
            acc = fmaf(wv.y, kv.y, acc);
            acc = fmaf(wv.z, kv.z, acc);
            acc = fmaf(wv.w, kv.w, acc);
        }
        pexS[w][lane + 64] = acc;
    }
    __asm__ __volatile__("s_waitcnt lgkmcnt(0)" ::: "memory");

    // exact rank (lowest-index tie-break); winners into LDS lists
    for (int e = lane; e < c; e += 64) {
        float ae = fabsf(pexS[w][e]);
        int   ne = pidxS[w][e];
        int rank = 0;
        for (int j = 0; j < c; ++j) {
            float aj = fabsf(pexS[w][j]);
            rank += ((aj > ae) || (aj == ae && pidxS[w][j] < ne)) ? 1 : 0;
        }
        if (rank < S_) {
            sidxS[w][rank] = ne;
            svalS[w][rank] = pexS[w][e];
        }
    }
    __asm__ __volatile__("s_waitcnt lgkmcnt(0)" ::: "memory");

    // emit winner lists; DIRECT scatter of low-half winners (that region was
    // zeroed by zero_y_low before the encoder and has no other writer)
    if (lane < S_) {
        int n = sidxS[w][lane];
        float v = svalS[w][lane];
        cidx[(size_t)row * S_ + lane] = n;
        cval[(size_t)row * S_ + lane] = v;
        if (n < 2048) yo[n] = v;
    }

    // fused decode: 2 dims per lane; WdT rows L2-resident (l-major)
    const float* wt = WdT + (size_t)l * N_ * M_;
    float acc0 = 0.0f, acc1 = 0.0f;
    #pragma unroll 4
    for (int j = 0; j < S_; ++j) {
        float v = svalS[w][j];
        const float* wrp = wt + (size_t)sidxS[w][j] * M_;
        acc0 = fmaf(v, wrp[lane], acc0);
        acc1 = fmaf(v, wrp[lane + 64], acc1);
    }
    khat[(size_t)row * M_ + lane]      = acc0;
    khat[(size_t)row * M_ + lane + 64] = acc1;
    float r0 = acc0 - kinS[w][lane];
    float r1 = acc1 - kinS[w][lane + 64];
    float s = r0 * r0 + r1 * r1;
    #pragma unroll
    for (int o = 32; o > 0; o >>= 1) s += __shfl_xor(s, o, 64);
    if (lane == 0) partial[row] = s;
}

// ---------------------------------------------------------------------------
// K4: deterministic reduction of 32768 partials -> loss (float4 loads)
// ---------------------------------------------------------------------------
__global__ __launch_bounds__(256) void reduce_loss(const float* __restrict__ partial,
                                                   float* __restrict__ out_loss) {
    __shared__ float red[256];
    int tid = threadIdx.x;
    float s = 0.0f;
    for (int i = tid; i < ROWS / 4; i += 256) {
        float4 v = reinterpret_cast<const float4*>(partial)[i];
        s += v.x + v.y + v.z + v.w;
    }
    red[tid] = s;
    __syncthreads();
    for (int off = 128; off > 0; off >>= 1) {
        if (tid < off) red[tid] += red[tid + off];
        __syncthreads();
    }
    if (tid == 0) out_loss[0] = red[0] / (float)((size_t)B_ * L_ * M_);
}

// ---------------------------------------------------------------------------
extern "C" void kernel_launch(void* const* d_in, const int* in_sizes, int n_in,
                              void* d_out, int out_size, void* d_ws, size_t ws_size,
                              hipStream_t stream) {
    const float* kin = (const float*)d_in[0];   // [B][L][M]
    const float* We  = (const float*)d_in[1];   // [L][N][M]
    // d_in[2] = b_e (unused by reference encode())
    const float* Wd  = (const float*)d_in[3];   // [L][M][N]
    const float* bd  = (const float*)d_in[4];   // [L][M]
    // d_in[5] = s (==32, hardcoded)

    float* out   = (float*)d_out;
    float* loss  = out;                                   // [1]
    float* khat  = out + 1;                               // [B*L*M]
    float* y_out = out + 1 + (size_t)B_ * L_ * M_;        // [B*L*N]

    // workspace layout (region0 shared: Wbf during encode, WdT after)
    char* ws = (char*)d_ws;
    unsigned short* Wbf = (unsigned short*)ws;                   // 32 MiB (in 64 MiB region0)
    float*          WdT = (float*)ws;                            // 64 MiB (aliases Wbf)
    unsigned short* Abf = (unsigned short*)(ws + (64u << 20));   // 8 MiB
    int*   cidx    = (int*)  (ws + (72u << 20));                 // 4 MiB
    float* cval    = (float*)(ws + (76u << 20));                 // 4 MiB
    float* cvec    = (float*)(ws + (80u << 20));                 // 512 KiB
    float* partial = (float*)(ws + (81u << 20));                 // 128 KiB

    // zero low halves of y first (approx lives in high halves)
    zero_y_low<<<2048, 256, 0, stream>>>(y_out);
    prep_w<<<dim3(N_ / 16, L_), 256, 0, stream>>>(We, bd, Wbf, cvec);
    prep_a<<<(B_ * L_ * M_) / 256, 256, 0, stream>>>(kin, Abf);
    encoder_mfma<<<dim3(N_ / 128, B_ / 128, L_), 256, 0, stream>>>(
        Abf, Wbf, cvec, (unsigned short*)y_out);
    // Wbf dead now; transpose overwrites region0 with WdT
    transpose_wd<<<dim3(N_ / 32, M_ / 32, L_), 256, 0, stream>>>(Wd, WdT);
    // wave-per-row selector + decoder (direct low-half scatter)
    topk_decode<<<ROWS / 4, 256, 0, stream>>>(y_out, We, WdT, kin, cvec,
                                              cidx, cval, khat, partial);
    // streaming finishers: zero high halves, then scatter high winners
    zero_y_high<<<2048, 256, 0, stream>>>(y_out);
    scatter_high<<<(ROWS * S_) / 256, 256, 0, stream>>>(y_out, cidx, cval);
    reduce_loss<<<1, 256, 0, stream>>>(partial, loss);
}